// Round 1
// baseline (227.850 us; speedup 1.0000x reference)
//
#include <hip/hip_runtime.h>

#define TAU 0.2f
#define VTH 0.3f

// x: [B, C, H, W, T] fp32, T = 8 innermost/contiguous.
// 33.5M floats = 8.4M float4. Fully-coalesced scheme:
//   lane i <-> float4 #i (unit stride, 16 B/lane on load AND store).
// float4 #i is half a pixel's timeline: t=0..3 if i even, t=4..7 if i odd.
//   Pass 1: every lane scans its 4 values from carry 0 -> half-scan carry s.
//   Handoff: odd lanes take the even neighbor's carry via __shfl_up(s, 1).
//   Pass 2: every lane re-scans with the true carry-in (0 for even lanes)
//           and stores its float4 of spikes, unit stride.
// All lanes run both passes uniformly (no divergence); even lanes' carry-in
// of 0 is their true initial condition, so pass 2 is exact for them too.
__global__ __launch_bounds__(256) void LIFSpike_73864847556979_kernel(
    const float4* __restrict__ x, float4* __restrict__ out, int n_vec) {
    int stride = gridDim.x * blockDim.x;
    for (int i = blockIdx.x * blockDim.x + threadIdx.x; i < n_vec; i += stride) {
        float4 v = x[i];
        float xv[4] = {v.x, v.y, v.z, v.w};

        // Pass 1: carry-only half scan (carry-in = 0).
        // s holds TAU * u * (1 - o) after each step.
        float s = 0.0f;
#pragma unroll
        for (int t = 0; t < 4; ++t) {
            float u = s + xv[t];
            s = (u - VTH > 0.0f) ? 0.0f : TAU * u;
        }

        // Hand the even lane's carry to its odd neighbor (same pixel).
        // Pairs are (lane 2k, lane 2k+1) -- never cross a wave boundary.
        float cin = __shfl_up(s, 1);
        if ((threadIdx.x & 1) == 0) cin = 0.0f;

        // Pass 2: real scan with the correct carry-in.
        float r0, r1, r2, r3;
        s = cin;
        {
            float u = s + xv[0];
            r0 = (u - VTH > 0.0f) ? 1.0f : 0.0f;
            s = (u - VTH > 0.0f) ? 0.0f : TAU * u;
        }
        {
            float u = s + xv[1];
            r1 = (u - VTH > 0.0f) ? 1.0f : 0.0f;
            s = (u - VTH > 0.0f) ? 0.0f : TAU * u;
        }
        {
            float u = s + xv[2];
            r2 = (u - VTH > 0.0f) ? 1.0f : 0.0f;
            s = (u - VTH > 0.0f) ? 0.0f : TAU * u;
        }
        {
            float u = s + xv[3];
            r3 = (u - VTH > 0.0f) ? 1.0f : 0.0f;
        }

        out[i] = make_float4(r0, r1, r2, r3);
    }
}

extern "C" void kernel_launch(void* const* d_in, const int* in_sizes, int n_in,
                              void* d_out, int out_size, void* d_ws, size_t ws_size,
                              hipStream_t stream) {
    const float4* x = (const float4*)d_in[0];
    float4* out = (float4*)d_out;
    int n_vec = in_sizes[0] / 4;  // total floats / 4

    int block = 256;
    long long need = ((long long)n_vec + block - 1) / block;
    int grid = (need > 2048) ? 2048 : (int)need;  // 8 blocks/CU, grid-stride

    LIFSpike_73864847556979_kernel<<<grid, block, 0, stream>>>(x, out, n_vec);
}

// Round 2
// 220.726 us; speedup vs baseline: 1.0323x; 1.0323x over previous
//
#include <hip/hip_runtime.h>

#define TAU 0.2f
#define VTH 0.3f

typedef __attribute__((ext_vector_type(4))) float f32x4;

// LIF half-scan over 4 timesteps: given carry-in cin, produce 4 spike outputs
// and the carry-out s = TAU*u*(1-o) after the last step.
__device__ __forceinline__ f32x4 lif4(f32x4 v, float cin, float* cout) {
    float s = cin;
    f32x4 r;
#pragma unroll
    for (int t = 0; t < 4; ++t) {
        float u = s + v[t];
        bool spike = (u - VTH) > 0.0f;
        r[t] = spike ? 1.0f : 0.0f;
        s = spike ? 0.0f : TAU * u;
    }
    *cout = s;
    return r;
}

// x: [B, C, H, W, T] fp32, T = 8 innermost/contiguous. 8.4M float4.
// Coalesced lane<->float4 mapping (16 B/lane unit stride on load AND store);
// each pixel's 8 timesteps = (even lane f4, odd lane f4) pair, stitched with
// one __shfl_up carry handoff. Two independent float4s per thread per loop
// iteration (i and i+stride) for 2x memory-level parallelism; nontemporal
// load/store since this is a single-pass stream with zero reuse.
__global__ __launch_bounds__(256) void LIFSpike_73864847556979_kernel(
    const f32x4* __restrict__ x, f32x4* __restrict__ out, int n_vec) {
    int tid = blockIdx.x * blockDim.x + threadIdx.x;
    int stride = gridDim.x * blockDim.x;
    bool even_lane = (threadIdx.x & 1) == 0;

    for (int i = tid; i < n_vec; i += 2 * stride) {
        int j = i + stride;
        bool hasb = (j < n_vec);

        f32x4 va = __builtin_nontemporal_load(&x[i]);
        f32x4 vb = {0.0f, 0.0f, 0.0f, 0.0f};
        if (hasb) vb = __builtin_nontemporal_load(&x[j]);

        // Pass 1: half-scan with carry-in 0 (exact for even lanes).
        float sa, sb;
        (void)lif4(va, 0.0f, &sa);
        (void)lif4(vb, 0.0f, &sb);

        // Carry handoff: odd lane gets even neighbor's carry-out.
        // Executed by all lanes (no divergence around the shuffle).
        float ca = __shfl_up(sa, 1);
        float cb = __shfl_up(sb, 1);
        if (even_lane) { ca = 0.0f; cb = 0.0f; }

        // Pass 2: exact scan with the true carry-in.
        float dump;
        f32x4 ra = lif4(va, ca, &dump);
        f32x4 rb = lif4(vb, cb, &dump);

        __builtin_nontemporal_store(ra, &out[i]);
        if (hasb) __builtin_nontemporal_store(rb, &out[j]);
    }
}

extern "C" void kernel_launch(void* const* d_in, const int* in_sizes, int n_in,
                              void* d_out, int out_size, void* d_ws, size_t ws_size,
                              hipStream_t stream) {
    const f32x4* x = (const f32x4*)d_in[0];
    f32x4* out = (f32x4*)d_out;
    int n_vec = in_sizes[0] / 4;  // total floats / 4

    int block = 256;
    long long need = ((long long)n_vec + block - 1) / block;
    int grid = (need > 2048) ? 2048 : (int)need;  // 8 blocks/CU, grid-stride

    LIFSpike_73864847556979_kernel<<<grid, block, 0, stream>>>(x, out, n_vec);
}